// Round 4
// baseline (2907.686 us; speedup 1.0000x reference)
//
#include <hip/hip_runtime.h>
#include <hip/hip_bf16.h>
#include <stdint.h>

// Binarized MLP: B=8192, D_IN=3072, H=2000 (pad 2048), C=10.
// L1 (exact, bf16 MFMA): Q=round(x*2^14)=d1*512+d0 digits exact in bf16;
//   K=6144 GEMM [d1*512|d0]@[s|s]^T -> Ti exact; residual K=3072 GEMM fuses
//   z1 = mean|W1|*2^-14*(Ti+Sr)+b1 in double.
// Layers 2-4: i8 MFMA on {0,1}x{+-1} — exact i32, BK=128. h4 in bf16.
// R9: kill the cg::grid_sync call. R7/R8 both compiled mega at VGPR=64 with
// scratch spill (MfmaUtil 7.6%) DESPITE __forceinline__ + waves_per_eu(4,4) —
// the surviving suspect is the __ockl_grid_sync call (call ABI forces a
// conservative register budget for the whole kernel). Replace with a manual
// inline grid barrier (__hip_atomic_* acq/rel + __threadfence, device scope —
// the G16-sanctioned cross-XCD mechanism). Coop kernel is now GEMM-only:
// prep/fc return to their proven standalone high-parallelism forms.
// Nodes: memset, prep, mega2(coop), fc = 5 vs R6's 8. R6 fallback if coop
// launch is rejected (also fires if regalloc ever drops below 4 blocks/CU).
typedef __bf16 bf16_t;
typedef __attribute__((ext_vector_type(8))) __bf16 bf16x8;
typedef __attribute__((ext_vector_type(4))) float f32x4;
typedef __attribute__((ext_vector_type(4))) int i32x4;
typedef __attribute__((ext_vector_type(8))) char i8x8;

#define GLD_LDS16(g, l) __builtin_amdgcn_global_load_lds( \
    (__attribute__((address_space(1))) void*)(g), \
    (__attribute__((address_space(3))) void*)(l), 16, 0, 0)

__device__ __forceinline__ void block_reduce_atomic_d(double v, double* dst) {
    #pragma unroll
    for (int off = 32; off > 0; off >>= 1) v += __shfl_down(v, off);
    __shared__ double rb[4];
    const int t = threadIdx.x;
    __syncthreads();                      // rb reuse guard (multiple calls per kernel)
    if ((t & 63) == 0) rb[t >> 6] = v;
    __syncthreads();
    if (t == 0) atomicAdd(dst, rb[0] + rb[1] + rb[2] + rb[3]);
}

// --- manual grid barrier: fully inlinable, no external calls (R9 fix) ---
// cnt/gen live in workspace (zeroed by the per-launch memset). Generation
// counter makes it reusable across the 3 barriers in one launch.
__device__ __forceinline__ void grid_bar(int* cnt, int* gen, int nblk) {
    __threadfence();                      // publish this block's writes (device scope)
    __syncthreads();                      // whole block arrived
    if (threadIdx.x == 0) {
        int g = __hip_atomic_load(gen, __ATOMIC_RELAXED, __HIP_MEMORY_SCOPE_AGENT);
        int prev = __hip_atomic_fetch_add(cnt, 1, __ATOMIC_ACQ_REL, __HIP_MEMORY_SCOPE_AGENT);
        if (prev == nblk - 1) {
            __hip_atomic_store(cnt, 0, __ATOMIC_RELAXED, __HIP_MEMORY_SCOPE_AGENT);
            __hip_atomic_store(gen, g + 1, __ATOMIC_RELEASE, __HIP_MEMORY_SCOPE_AGENT);
        } else {
            while (__hip_atomic_load(gen, __ATOMIC_ACQUIRE, __HIP_MEMORY_SCOPE_AGENT) == g)
                __builtin_amdgcn_s_sleep(2);
        }
    }
    __syncthreads();
    __threadfence();                      // reader-side invalidate (stale L1/L2 lines)
}

// --- prep row bodies (return per-thread partial |W| sums) ---
__device__ __forceinline__ double prep_w1_row(
    const float* __restrict__ W, int r, bf16_t* __restrict__ S)
{
    const int t = threadIdx.x;
    double sl = 0.0;
    for (int cb = t * 8; cb < 3072; cb += 2048) {
        bf16x8 o;
        if (r < 2000) {
            #pragma unroll
            for (int j = 0; j < 8; ++j) {
                float v = W[(size_t)r * 3072 + cb + j];
                sl += (double)fabsf(v);
                o[j] = (bf16_t)(v > 0.f ? 1.f : (v < 0.f ? -1.f : 0.f));
            }
        } else {
            #pragma unroll
            for (int j = 0; j < 8; ++j) o[j] = (bf16_t)0.f;
        }
        *(bf16x8*)&S[(size_t)r * 6144 + cb] = o;
        *(bf16x8*)&S[(size_t)r * 6144 + 3072 + cb] = o;
    }
    return sl;
}

__device__ __forceinline__ double prep_wi8_row(
    const float* __restrict__ W, int r, int8_t* __restrict__ S)
{
    const int t = threadIdx.x;
    const int cb = t * 8;
    double sl = 0.0;
    i8x8 o;
    if (r < 2000) {
        #pragma unroll
        for (int j = 0; j < 8; ++j) {
            int c = cb + j;
            float v = (c < 2000) ? W[(size_t)r * 2000 + c] : 0.f;
            sl += (double)fabsf(v);
            o[j] = (char)(v > 0.f ? 1 : (v < 0.f ? -1 : 0));
        }
    } else {
        #pragma unroll
        for (int j = 0; j < 8; ++j) o[j] = 0;
    }
    *(i8x8*)&S[(size_t)r * 2048 + cb] = o;
    return sl;
}

__device__ __forceinline__ void prep_x_row(
    const float* __restrict__ x, int r, bf16_t* __restrict__ XLi, bf16_t* __restrict__ XLr)
{
    const int t = threadIdx.x;
    for (int cb = t * 8; cb < 3072; cb += 2048) {
        float4 v0 = *(const float4*)&x[(size_t)r * 3072 + cb];
        float4 v1 = *(const float4*)&x[(size_t)r * 3072 + cb + 4];
        float xv[8] = {v0.x, v0.y, v0.z, v0.w, v1.x, v1.y, v1.z, v1.w};
        bf16x8 hi, lo, re;
        #pragma unroll
        for (int j = 0; j < 8; ++j) {
            int Q = (int)lrintf(xv[j] * 16384.f);           // x * 2^14
            int d0 = ((Q + 256) & 511) - 256;               // [-256,255], exact bf16
            int d1 = (Q - d0) / 512;                        // |d1|<=~182, exact bf16
            float rr = xv[j] - (float)Q * (1.f / 16384.f);  // exact (Sterbenz)
            hi[j] = (bf16_t)(float)(d1 * 512);              // exact (pow2 shift)
            lo[j] = (bf16_t)(float)d0;
            re[j] = (bf16_t)(rr * 16384.f);                 // in [-.5,.5]
        }
        *(bf16x8*)&XLi[(size_t)r * 6144 + cb]        = hi;
        *(bf16x8*)&XLi[(size_t)r * 6144 + 3072 + cb] = lo;
        *(bf16x8*)&XLr[(size_t)r * 3072 + cb]        = re;
    }
}

// --- bf16 GEMM phase: C = A @ B^T, 128x128x64 tiles, flattened 1024-block grid.
// rawOut mode writes fp32 acc. Else epilogue (double):
// z = sumW*invDivW*extraScale*(acc+addPlane?) + bias; binOut i8 {0,1};
// atomic double sum(relu z). Bit-identical to R6's gemm_bin.
__device__ __forceinline__ void gemm_bin_phase(
    bf16_t* sA, bf16_t* sB,
    const bf16_t* __restrict__ A, const bf16_t* __restrict__ B, int K, int ldB,
    float* __restrict__ rawOut,
    const float* __restrict__ addPlane,
    const double* __restrict__ sumW, double invDivW, double extraScale,
    const float* __restrict__ bias,
    int8_t* __restrict__ binOut,
    double* __restrict__ habs)
{
    const int t = threadIdx.x;
    const int lane = t & 63;
    const int wave = t >> 6;
    const int wr = wave >> 1, wc = wave & 1;
    const int qa = lane >> 4, rA = lane & 15;
    const int blk = (int)blockIdx.x;
    const size_t bm = (size_t)(blk >> 4) * 128, bn = (size_t)(blk & 15) * 128;

    f32x4 acc[4][4] = {};

    const bf16_t* Abase = A + bm * (size_t)K;
    const bf16_t* Bbase = B + bn * (size_t)ldB;

    const int swz = rA & 7;
    const int offk0 = ((0 + qa) ^ swz) * 8;
    const int offk1 = ((4 + qa) ^ swz) * 8;
    const int arow = wr * 64 + rA;
    const int brow = wc * 64 + rA;

    for (int k0 = 0; k0 < K; k0 += 64) {
        #pragma unroll
        for (int i = 0; i < 4; ++i) {
            int c = i * 256 + t;
            int row = c >> 3, cc = c & 7;
            int ccg = cc ^ (row & 7);
            GLD_LDS16(Abase + (size_t)row * K + k0 + ccg * 8, &sA[c * 8]);
        }
        #pragma unroll
        for (int i = 0; i < 4; ++i) {
            int c = i * 256 + t;
            int row = c >> 3, cc = c & 7;
            int ccg = cc ^ (row & 7);
            GLD_LDS16(Bbase + (size_t)row * ldB + k0 + ccg * 8, &sB[c * 8]);
        }
        __syncthreads();

        bf16x8 fa[4][2], fb[4][2];
        #pragma unroll
        for (int i = 0; i < 4; ++i) {
            fa[i][0] = *(const bf16x8*)&sA[(arow + i * 16) * 64 + offk0];
            fa[i][1] = *(const bf16x8*)&sA[(arow + i * 16) * 64 + offk1];
            fb[i][0] = *(const bf16x8*)&sB[(brow + i * 16) * 64 + offk0];
            fb[i][1] = *(const bf16x8*)&sB[(brow + i * 16) * 64 + offk1];
        }
        #pragma unroll
        for (int i = 0; i < 4; ++i)
            #pragma unroll
            for (int j = 0; j < 4; ++j) {
                acc[i][j] = __builtin_amdgcn_mfma_f32_16x16x32_bf16(fa[i][0], fb[j][0], acc[i][j], 0, 0, 0);
                acc[i][j] = __builtin_amdgcn_mfma_f32_16x16x32_bf16(fa[i][1], fb[j][1], acc[i][j], 0, 0, 0);
            }
        __syncthreads();
    }

    if (rawOut) {   // exact integer partial sums in fp32
        #pragma unroll
        for (int i = 0; i < 4; ++i)
            #pragma unroll
            for (int j = 0; j < 4; ++j)
                #pragma unroll
                for (int rr = 0; rr < 4; ++rr) {
                    int m = (int)bm + wr * 64 + i * 16 + qa * 4 + rr;
                    int n = (int)bn + wc * 64 + j * 16 + rA;
                    rawOut[(size_t)m * 2048 + n] = acc[i][j][rr];
                }
        return;
    }

    const double scale = sumW[0] * invDivW * extraScale;
    double hs = 0.0;
    #pragma unroll
    for (int i = 0; i < 4; ++i) {
        #pragma unroll
        for (int j = 0; j < 4; ++j) {
            #pragma unroll
            for (int rr = 0; rr < 4; ++rr) {
                // C/D layout: col = lane&15, row = (lane>>4)*4 + reg
                int m = (int)bm + wr * 64 + i * 16 + qa * 4 + rr;
                int n = (int)bn + wc * 64 + j * 16 + rA;
                size_t idx = (size_t)m * 2048 + n;
                double s = (double)acc[i][j][rr];
                if (addPlane) s += (double)addPlane[idx];
                double z = s * scale + (n < 2000 ? (double)bias[n] : -1.0);
                binOut[idx] = (int8_t)(z > 0.0 ? 1 : 0);
                if (n < 2000 && z > 0.0) hs += z;
            }
        }
    }
    if (habs) block_reduce_atomic_d(hs, habs);
}

// --- i8 GEMM phase: A:[8192][2048] {0,1}, B:[2048][2048] {+-1,0}.
// 128x128 tile, BK=128, XOR-swizzled 16B chunks. Bit-identical to R6's gemm_i8.
__device__ __forceinline__ void gemm_i8_phase(
    int8_t* sA, int8_t* sB,
    const int8_t* __restrict__ A, const int8_t* __restrict__ B,
    const double* __restrict__ sumW, double invDivW,
    const double* __restrict__ sumH, double invDivH,
    const float* __restrict__ bias,
    int8_t* __restrict__ binOut, bf16_t* __restrict__ hOut,
    double* __restrict__ habs)
{
    const int K = 2048;                           // bytes per row
    const int t = threadIdx.x;
    const int lane = t & 63;
    const int wave = t >> 6;
    const int wr = wave >> 1, wc = wave & 1;
    const int qa = lane >> 4, rA = lane & 15;
    const int blk = (int)blockIdx.x;
    const size_t bm = (size_t)(blk >> 4) * 128, bn = (size_t)(blk & 15) * 128;

    i32x4 acc[4][4] = {};

    const int8_t* Abase = A + bm * (size_t)K;
    const int8_t* Bbase = B + bn * (size_t)K;

    const int swz = rA & 7;
    const int offb0 = ((0 + qa) ^ swz) * 16;      // k-half 0: k in [0,64)
    const int offb1 = ((4 + qa) ^ swz) * 16;      // k-half 1: k in [64,128)
    const int arow = wr * 64 + rA;
    const int brow = wc * 64 + rA;

    for (int k0 = 0; k0 < K; k0 += 128) {
        #pragma unroll
        for (int i = 0; i < 4; ++i) {
            int c = i * 256 + t;
            int row = c >> 3, cc = c & 7;
            int ccg = cc ^ (row & 7);
            GLD_LDS16(Abase + (size_t)row * K + k0 + ccg * 16, &sA[c * 16]);
        }
        #pragma unroll
        for (int i = 0; i < 4; ++i) {
            int c = i * 256 + t;
            int row = c >> 3, cc = c & 7;
            int ccg = cc ^ (row & 7);
            GLD_LDS16(Bbase + (size_t)row * K + k0 + ccg * 16, &sB[c * 16]);
        }
        __syncthreads();

        {   // k-half 0
            i32x4 fa[4], fb[4];
            #pragma unroll
            for (int i = 0; i < 4; ++i) {
                fa[i] = *(const i32x4*)&sA[(arow + i * 16) * 128 + offb0];
                fb[i] = *(const i32x4*)&sB[(brow + i * 16) * 128 + offb0];
            }
            #pragma unroll
            for (int i = 0; i < 4; ++i)
                #pragma unroll
                for (int j = 0; j < 4; ++j)
                    acc[i][j] = __builtin_amdgcn_mfma_i32_16x16x64_i8(fa[i], fb[j], acc[i][j], 0, 0, 0);
        }
        {   // k-half 1
            i32x4 fa[4], fb[4];
            #pragma unroll
            for (int i = 0; i < 4; ++i) {
                fa[i] = *(const i32x4*)&sA[(arow + i * 16) * 128 + offb1];
                fb[i] = *(const i32x4*)&sB[(brow + i * 16) * 128 + offb1];
            }
            #pragma unroll
            for (int i = 0; i < 4; ++i)
                #pragma unroll
                for (int j = 0; j < 4; ++j)
                    acc[i][j] = __builtin_amdgcn_mfma_i32_16x16x64_i8(fa[i], fb[j], acc[i][j], 0, 0, 0);
        }
        __syncthreads();
    }

    const double scale = sumW[0] * invDivW * sumH[0] * invDivH;
    double hs = 0.0;
    #pragma unroll
    for (int i = 0; i < 4; ++i) {
        #pragma unroll
        for (int j = 0; j < 4; ++j) {
            #pragma unroll
            for (int rr = 0; rr < 4; ++rr) {
                int m = (int)bm + wr * 64 + i * 16 + qa * 4 + rr;
                int n = (int)bn + wc * 64 + j * 16 + rA;
                size_t idx = (size_t)m * 2048 + n;
                double z = (double)acc[i][j][rr] * scale +
                           (n < 2000 ? (double)bias[n] : -1.0);
                if (binOut) binOut[idx] = (int8_t)(z > 0.0 ? 1 : 0);
                if (hOut)   hOut[idx] = (bf16_t)(float)(z > 0.0 ? z : 0.0);
                if (n < 2000 && z > 0.0) hs += z;
            }
        }
    }
    if (habs) block_reduce_atomic_d(hs, habs);
}

// one row of: out[r][:] = h4[r, :2000] @ W5.T + b5
__device__ __forceinline__ void fc_row(
    const bf16_t* __restrict__ h4, const float* __restrict__ W5,
    const float* __restrict__ b5, float* __restrict__ out, int r)
{
    const int t = threadIdx.x;
    float acc[10] = {};
    for (int k = t; k < 2000; k += 256) {
        float a = (float)h4[(size_t)r * 2048 + k];
        #pragma unroll
        for (int c = 0; c < 10; ++c) acc[c] += a * W5[c * 2000 + k];
    }
    __shared__ float red[4][10];
    #pragma unroll
    for (int c = 0; c < 10; ++c) {
        float v = acc[c];
        #pragma unroll
        for (int off = 32; off > 0; off >>= 1) v += __shfl_down(v, off);
        if ((t & 63) == 0) red[t >> 6][c] = v;
    }
    __syncthreads();
    if (t < 10) out[(size_t)r * 10 + t] = red[0][t] + red[1][t] + red[2][t] + red[3][t] + b5[t];
}

// ============ cooperative GEMM-only kernel: 5 GEMM phases, 3 barriers =======
// grid 1024 x 256 @ (256,4) + waves_per_eu(4,4): 4 blocks/CU x 256 CU
// co-resident. NO external calls anywhere in the body (R9: the cg grid.sync
// call was the prime suspect for the VGPR=64 cap).
__global__ __launch_bounds__(256, 4) __attribute__((amdgpu_waves_per_eu(4, 4)))
void mega2(const bf16_t* XLi, const bf16_t* XLr, const bf16_t* sW1,
           const int8_t* sW2, const int8_t* sW3, const int8_t* sW4,
           float* Ti, double* scD,
           const float* b1, const float* b2, const float* b3, const float* b4,
           int8_t* p0, int8_t* p1, bf16_t* h4)
{
    __shared__ __align__(16) char smem[32768];
    bf16_t* sA16 = (bf16_t*)smem;  bf16_t* sB16 = (bf16_t*)(smem + 16384);
    int8_t* sA8  = (int8_t*)smem;  int8_t* sB8  = (int8_t*)(smem + 16384);
    int* cnt = (int*)scD + 32;   // workspace byte 128 (memset-zeroed per launch)
    int* gen = (int*)scD + 48;   // workspace byte 192

    // L1a: Ti = XLi @ sW1^T (K=6144), raw fp32 (exact ints)
    gemm_bin_phase(sA16, sB16, XLi, sW1, 6144, 6144, Ti, nullptr,
                   nullptr, 0.0, 1.0, nullptr, nullptr, nullptr);
    __syncthreads();
    // L1b: residual GEMM + combine. Ti read is same-thread/same-address.
    gemm_bin_phase(sA16, sB16, XLr, sW1, 3072, 6144, nullptr, Ti,
                   scD + 0, 1.0 / 6144000.0, 1.0 / 16384.0, b1, p0, scD + 4);
    grid_bar(cnt, gen, 1024);
    // L2-L4 (i8). p1 aliases XLi (dead after L1), h4 aliases Ti (dead after L1b).
    gemm_i8_phase(sA8, sB8, p0, sW2, scD + 1, 1.0 / 4000000.0,
                  scD + 4, 1.0 / 16384000.0, b2, p1, nullptr, scD + 5);
    grid_bar(cnt, gen, 1024);
    gemm_i8_phase(sA8, sB8, p1, sW3, scD + 2, 1.0 / 4000000.0,
                  scD + 5, 1.0 / 16384000.0, b3, p0, nullptr, scD + 6);
    grid_bar(cnt, gen, 1024);
    gemm_i8_phase(sA8, sB8, p0, sW4, scD + 3, 1.0 / 4000000.0,
                  scD + 6, 1.0 / 16384000.0, b4, nullptr, h4, nullptr);
    // h4 consumed by the separate fc kernel (node boundary = sync)
}

// ================= standalone kernels (prep/fc + R6 fallback path) ==========
__global__ __launch_bounds__(256) void k_prep(
    const float* __restrict__ W1, const float* __restrict__ W2,
    const float* __restrict__ W3, const float* __restrict__ W4,
    const float* __restrict__ x,
    bf16_t* __restrict__ sW1, int8_t* __restrict__ sW2,
    int8_t* __restrict__ sW3, int8_t* __restrict__ sW4,
    bf16_t* __restrict__ XLi, bf16_t* __restrict__ XLr,
    double* __restrict__ scD)
{
    const int g = blockIdx.x;
    if      (g < 2048)  block_reduce_atomic_d(prep_w1_row(W1, g, sW1), scD + 0);
    else if (g < 4096)  block_reduce_atomic_d(prep_wi8_row(W2, g - 2048, sW2), scD + 1);
    else if (g < 6144)  block_reduce_atomic_d(prep_wi8_row(W3, g - 4096, sW3), scD + 2);
    else if (g < 8192)  block_reduce_atomic_d(prep_wi8_row(W4, g - 6144, sW4), scD + 3);
    else                prep_x_row(x, g - 8192, XLi, XLr);
}

__global__ __launch_bounds__(256, 4) void k_gemm_bin(
    const bf16_t* A, const bf16_t* B, int K, int ldB,
    float* rawOut, const float* addPlane,
    const double* sumW, double invDivW, double extraScale,
    const float* bias, int8_t* binOut, double* habs)
{
    __shared__ __align__(16) char smem[32768];
    gemm_bin_phase((bf16_t*)smem, (bf16_t*)(smem + 16384), A, B, K, ldB,
                   rawOut, addPlane, sumW, invDivW, extraScale, bias, binOut, habs);
}

__global__ __launch_bounds__(256, 4) void k_gemm_i8(
    const int8_t* A, const int8_t* B,
    const double* sumW, double invDivW,
    const double* sumH, double invDivH,
    const float* bias, int8_t* binOut, bf16_t* hOut, double* habs)
{
    __shared__ __align__(16) char smem[32768];
    gemm_i8_phase((int8_t*)smem, (int8_t*)(smem + 16384), A, B,
                  sumW, invDivW, sumH, invDivH, bias, binOut, hOut, habs);
}

__global__ __launch_bounds__(256) void k_fc(
    const bf16_t* h4, const float* W5, const float* b5, float* out)
{
    fc_row(h4, W5, b5, out, (int)blockIdx.x);
}

extern "C" void kernel_launch(void* const* d_in, const int* in_sizes, int n_in,
                              void* d_out, int out_size, void* d_ws, size_t ws_size,
                              hipStream_t stream)
{
    const float* x  = (const float*)d_in[0];
    const float* W1 = (const float*)d_in[1];
    const float* b1 = (const float*)d_in[2];
    const float* W2 = (const float*)d_in[3];
    const float* b2 = (const float*)d_in[4];
    const float* W3 = (const float*)d_in[5];
    const float* b3 = (const float*)d_in[6];
    const float* W4 = (const float*)d_in[7];
    const float* b4 = (const float*)d_in[8];
    const float* W5 = (const float*)d_in[9];
    const float* b5 = (const float*)d_in[10];
    float* out = (float*)d_out;
    (void)ws_size; (void)in_sizes; (void)n_in; (void)out_size;

    const size_t PH = (size_t)8192 * 2048;

    // Workspace layout unchanged from R6 (260.3 MiB total; 264 proven safe)
    // bytes [0..56): scD[0..6]; byte 128: grid-barrier cnt; byte 192: gen.
    char* w = (char*)d_ws;
    double* scD = (double*)w;
    size_t off = 256;
    bf16_t* XLi = (bf16_t*)(w + off); off += (size_t)8192 * 6144 * 2;  // 96 MiB
    bf16_t* XLr = (bf16_t*)(w + off); off += (size_t)8192 * 3072 * 2;  // 48 MiB
    bf16_t* sW1 = (bf16_t*)(w + off); off += (size_t)2048 * 6144 * 2;  // 24 MiB [s|s]
    float*  Ti  = (float*)(w + off);  off += PH * 4;                   // 64 MiB
    int8_t* p0  = (int8_t*)(w + off); off += PH;                       // 16 MiB
    int8_t* sW2 = (int8_t*)(w + off); off += (size_t)2048 * 2048;      // 4 MiB
    int8_t* sW3 = (int8_t*)(w + off); off += (size_t)2048 * 2048;      // 4 MiB
    int8_t* sW4 = (int8_t*)(w + off); off += (size_t)2048 * 2048;      // 4 MiB
    int8_t* p1  = (int8_t*)XLi;                    // XLi dead after L1 GEMMs
    bf16_t* h4  = (bf16_t*)Ti;                     // Ti dead after L1res epilogue

    hipMemsetAsync(w, 0, 256, stream);             // scD + barrier state

    // prep at full parallelism (proven R6 form)
    k_prep<<<16384, 256, 0, stream>>>(W1, W2, W3, W4, x,
                                      sW1, sW2, sW3, sW4, XLi, XLr, scD);

    void* kargs[] = {
        (void*)&XLi, (void*)&XLr, (void*)&sW1,
        (void*)&sW2, (void*)&sW3, (void*)&sW4,
        (void*)&Ti, (void*)&scD,
        (void*)&b1, (void*)&b2, (void*)&b3, (void*)&b4,
        (void*)&p0, (void*)&p1, (void*)&h4
    };
    hipError_t cerr = hipLaunchCooperativeKernel(
        reinterpret_cast<void*>(mega2), dim3(1024), dim3(256), kargs, 0, stream);

    if (cerr == hipSuccess) {
        k_fc<<<8192, 256, 0, stream>>>(h4, W5, b5, out);
    } else {
        // R6 fallback: separate GEMM dispatches, bit-identical numerics.
        k_gemm_bin<<<1024, 256, 0, stream>>>(XLi, sW1, 6144, 6144, Ti, nullptr,
                                             nullptr, 0.0, 1.0, nullptr, nullptr, nullptr);
        k_gemm_bin<<<1024, 256, 0, stream>>>(XLr, sW1, 3072, 6144, nullptr, Ti,
                                             scD + 0, 1.0 / 6144000.0, 1.0 / 16384.0,
                                             b1, p0, scD + 4);
        k_gemm_i8<<<1024, 256, 0, stream>>>(p0, sW2,
                                            scD + 1, 1.0 / 4000000.0, scD + 4, 1.0 / 16384000.0,
                                            b2, p1, nullptr, scD + 5);
        k_gemm_i8<<<1024, 256, 0, stream>>>(p1, sW3,
                                            scD + 2, 1.0 / 4000000.0, scD + 5, 1.0 / 16384000.0,
                                            b3, p0, nullptr, scD + 6);
        k_gemm_i8<<<1024, 256, 0, stream>>>(p0, sW4,
                                            scD + 3, 1.0 / 4000000.0, scD + 6, 1.0 / 16384000.0,
                                            b4, nullptr, h4, nullptr);
        k_fc<<<8192, 256, 0, stream>>>(h4, W5, b5, out);
    }
}

// Round 5
// 856.869 us; speedup vs baseline: 3.3934x; 3.3934x over previous
//
#include <hip/hip_runtime.h>
#include <hip/hip_bf16.h>
#include <stdint.h>

// Binarized MLP: B=8192, D_IN=3072, H=2000 (pad 2048), C=10.
// L1 (exact, bf16 MFMA): Q=round(x*2^14)=d1*512+d0 digits exact in bf16;
//   K=6144 GEMM [d1*512|d0]@[s|s]^T -> Ti exact; residual K=3072 GEMM fuses
//   z1 = mean|W1|*2^-14*(Ti+Sr)+b1 in double.
// Layers 2-4: i8 MFMA on {0,1}x{+-1} — exact i32, BK=128. h4 in bf16.
// R10: re-baseline. R7-R9 (cooperative mega-kernel, 3 variants) all hit the
// same codegen wall: VGPR_Count=64 with scratch spill in the merged kernel,
// MfmaUtil 6-8%, 2.2-2.9ms — 2.6-3.4x WORSE than this 8-node R6 structure
// (853.9us, proven). Coop path abandoned. This is the R6 kernel verbatim,
// resubmitted to (a) recover the baseline and (b) get per-dispatch rocprof
// counters in THIS session to direct the next optimization (L1 GEMM schedule).
typedef __bf16 bf16_t;
typedef __attribute__((ext_vector_type(8))) __bf16 bf16x8;
typedef __attribute__((ext_vector_type(4))) float f32x4;
typedef __attribute__((ext_vector_type(4))) int i32x4;
typedef __attribute__((ext_vector_type(8))) char i8x8;

#define GLD_LDS16(g, l) __builtin_amdgcn_global_load_lds( \
    (__attribute__((address_space(1))) void*)(g), \
    (__attribute__((address_space(3))) void*)(l), 16, 0, 0)

__device__ __forceinline__ void block_reduce_atomic_d(double v, double* dst) {
    #pragma unroll
    for (int off = 32; off > 0; off >>= 1) v += __shfl_down(v, off);
    __shared__ double rb[4];
    const int t = threadIdx.x;
    if ((t & 63) == 0) rb[t >> 6] = v;
    __syncthreads();
    if (t == 0) atomicAdd(dst, rb[0] + rb[1] + rb[2] + rb[3]);
}

// --- fused prep: one dispatch, 16384 blocks ---
__device__ __forceinline__ void prep_w1_row(
    const float* __restrict__ W, int r, bf16_t* __restrict__ S, double* sumOut)
{
    const int t = threadIdx.x;
    double sl = 0.0;
    for (int cb = t * 8; cb < 3072; cb += 2048) {
        bf16x8 o;
        if (r < 2000) {
            #pragma unroll
            for (int j = 0; j < 8; ++j) {
                float v = W[(size_t)r * 3072 + cb + j];
                sl += (double)fabsf(v);
                o[j] = (bf16_t)(v > 0.f ? 1.f : (v < 0.f ? -1.f : 0.f));
            }
        } else {
            #pragma unroll
            for (int j = 0; j < 8; ++j) o[j] = (bf16_t)0.f;
        }
        *(bf16x8*)&S[(size_t)r * 6144 + cb] = o;
        *(bf16x8*)&S[(size_t)r * 6144 + 3072 + cb] = o;
    }
    block_reduce_atomic_d(sl, sumOut);
}

__device__ __forceinline__ void prep_wi8_row(
    const float* __restrict__ W, int r, int8_t* __restrict__ S, double* sumOut)
{
    const int t = threadIdx.x;
    const int cb = t * 8;
    double sl = 0.0;
    i8x8 o;
    if (r < 2000) {
        #pragma unroll
        for (int j = 0; j < 8; ++j) {
            int c = cb + j;
            float v = (c < 2000) ? W[(size_t)r * 2000 + c] : 0.f;
            sl += (double)fabsf(v);
            o[j] = (char)(v > 0.f ? 1 : (v < 0.f ? -1 : 0));
        }
    } else {
        #pragma unroll
        for (int j = 0; j < 8; ++j) o[j] = 0;
    }
    *(i8x8*)&S[(size_t)r * 2048 + cb] = o;
    block_reduce_atomic_d(sl, sumOut);
}

__device__ __forceinline__ void prep_x_row(
    const float* __restrict__ x, int r, bf16_t* __restrict__ XLi, bf16_t* __restrict__ XLr)
{
    const int t = threadIdx.x;
    for (int cb = t * 8; cb < 3072; cb += 2048) {
        float4 v0 = *(const float4*)&x[(size_t)r * 3072 + cb];
        float4 v1 = *(const float4*)&x[(size_t)r * 3072 + cb + 4];
        float xv[8] = {v0.x, v0.y, v0.z, v0.w, v1.x, v1.y, v1.z, v1.w};
        bf16x8 hi, lo, re;
        #pragma unroll
        for (int j = 0; j < 8; ++j) {
            int Q = (int)lrintf(xv[j] * 16384.f);           // x * 2^14
            int d0 = ((Q + 256) & 511) - 256;               // [-256,255], exact bf16
            int d1 = (Q - d0) / 512;                        // |d1|<=~182, exact bf16
            float rr = xv[j] - (float)Q * (1.f / 16384.f);  // exact (Sterbenz)
            hi[j] = (bf16_t)(float)(d1 * 512);              // exact (pow2 shift)
            lo[j] = (bf16_t)(float)d0;
            re[j] = (bf16_t)(rr * 16384.f);                 // in [-.5,.5]
        }
        *(bf16x8*)&XLi[(size_t)r * 6144 + cb]        = hi;
        *(bf16x8*)&XLi[(size_t)r * 6144 + 3072 + cb] = lo;
        *(bf16x8*)&XLr[(size_t)r * 3072 + cb]        = re;
    }
}

__global__ __launch_bounds__(256) void prep_all(
    const float* __restrict__ W1, const float* __restrict__ W2,
    const float* __restrict__ W3, const float* __restrict__ W4,
    const float* __restrict__ x,
    bf16_t* __restrict__ sW1, int8_t* __restrict__ sW2,
    int8_t* __restrict__ sW3, int8_t* __restrict__ sW4,
    bf16_t* __restrict__ XLi, bf16_t* __restrict__ XLr,
    double* __restrict__ scD)
{
    const int g = blockIdx.x;
    if      (g < 2048)  prep_w1_row(W1, g, sW1, scD + 0);
    else if (g < 4096)  prep_wi8_row(W2, g - 2048, sW2, scD + 1);
    else if (g < 6144)  prep_wi8_row(W3, g - 4096, sW3, scD + 2);
    else if (g < 8192)  prep_wi8_row(W4, g - 6144, sW4, scD + 3);
    else                prep_x_row(x, g - 8192, XLi, XLr);
}

// bf16 GEMM C = A @ B^T, 128x128x64 tiles. rawOut mode writes fp32 acc.
// Epilogue (double): z = sumW*invDivW*extraScale*(acc+addPlane?) + bias;
// binOut i8 {0,1}; atomic double sum(relu z).
__global__ __launch_bounds__(256, 4) void gemm_bin(
    const bf16_t* __restrict__ A, const bf16_t* __restrict__ B, int K, int ldB,
    float* __restrict__ rawOut,
    const float* __restrict__ addPlane,
    const double* __restrict__ sumW, double invDivW, double extraScale,
    const float* __restrict__ bias,
    int8_t* __restrict__ binOut,
    double* __restrict__ habs)
{
    __shared__ __align__(16) bf16_t sA[128 * 64];
    __shared__ __align__(16) bf16_t sB[128 * 64];
    const int t = threadIdx.x;
    const int lane = t & 63;
    const int wave = t >> 6;
    const int wr = wave >> 1, wc = wave & 1;
    const int qa = lane >> 4, rA = lane & 15;
    const size_t bm = (size_t)blockIdx.y * 128, bn = (size_t)blockIdx.x * 128;

    f32x4 acc[4][4] = {};

    const bf16_t* Abase = A + bm * (size_t)K;
    const bf16_t* Bbase = B + bn * (size_t)ldB;

    const int swz = rA & 7;
    const int offk0 = ((0 + qa) ^ swz) * 8;
    const int offk1 = ((4 + qa) ^ swz) * 8;
    const int arow = wr * 64 + rA;
    const int brow = wc * 64 + rA;

    for (int k0 = 0; k0 < K; k0 += 64) {
        #pragma unroll
        for (int i = 0; i < 4; ++i) {
            int c = i * 256 + t;
            int row = c >> 3, cc = c & 7;
            int ccg = cc ^ (row & 7);
            GLD_LDS16(Abase + (size_t)row * K + k0 + ccg * 8, &sA[c * 8]);
        }
        #pragma unroll
        for (int i = 0; i < 4; ++i) {
            int c = i * 256 + t;
            int row = c >> 3, cc = c & 7;
            int ccg = cc ^ (row & 7);
            GLD_LDS16(Bbase + (size_t)row * ldB + k0 + ccg * 8, &sB[c * 8]);
        }
        __syncthreads();

        bf16x8 fa[4][2], fb[4][2];
        #pragma unroll
        for (int i = 0; i < 4; ++i) {
            fa[i][0] = *(const bf16x8*)&sA[(arow + i * 16) * 64 + offk0];
            fa[i][1] = *(const bf16x8*)&sA[(arow + i * 16) * 64 + offk1];
            fb[i][0] = *(const bf16x8*)&sB[(brow + i * 16) * 64 + offk0];
            fb[i][1] = *(const bf16x8*)&sB[(brow + i * 16) * 64 + offk1];
        }
        #pragma unroll
        for (int i = 0; i < 4; ++i)
            #pragma unroll
            for (int j = 0; j < 4; ++j) {
                acc[i][j] = __builtin_amdgcn_mfma_f32_16x16x32_bf16(fa[i][0], fb[j][0], acc[i][j], 0, 0, 0);
                acc[i][j] = __builtin_amdgcn_mfma_f32_16x16x32_bf16(fa[i][1], fb[j][1], acc[i][j], 0, 0, 0);
            }
        __syncthreads();
    }

    if (rawOut) {   // exact integer partial sums in fp32
        #pragma unroll
        for (int i = 0; i < 4; ++i)
            #pragma unroll
            for (int j = 0; j < 4; ++j)
                #pragma unroll
                for (int rr = 0; rr < 4; ++rr) {
                    int m = (int)bm + wr * 64 + i * 16 + qa * 4 + rr;
                    int n = (int)bn + wc * 64 + j * 16 + rA;
                    rawOut[(size_t)m * 2048 + n] = acc[i][j][rr];
                }
        return;
    }

    const double scale = sumW[0] * invDivW * extraScale;
    double hs = 0.0;
    #pragma unroll
    for (int i = 0; i < 4; ++i) {
        #pragma unroll
        for (int j = 0; j < 4; ++j) {
            #pragma unroll
            for (int rr = 0; rr < 4; ++rr) {
                // C/D layout: col = lane&15, row = (lane>>4)*4 + reg
                int m = (int)bm + wr * 64 + i * 16 + qa * 4 + rr;
                int n = (int)bn + wc * 64 + j * 16 + rA;
                size_t idx = (size_t)m * 2048 + n;
                double s = (double)acc[i][j][rr];
                if (addPlane) s += (double)addPlane[idx];
                double z = s * scale + (n < 2000 ? (double)bias[n] : -1.0);
                binOut[idx] = (int8_t)(z > 0.0 ? 1 : 0);
                if (n < 2000 && z > 0.0) hs += z;
            }
        }
    }
    if (habs) block_reduce_atomic_d(hs, habs);
}

// i8 GEMM C = A @ B^T, A:[8192][2048] {0,1}, B:[2048][2048] {+-1,0}.
// 128x128 tile, BK=128, XOR-swizzled 16B chunks. Fragment loads split per
// k-half (32 live frag VGPRs instead of 64; integer sums order-independent).
__global__ __launch_bounds__(256, 4) void gemm_i8(
    const int8_t* __restrict__ A, const int8_t* __restrict__ B,
    const double* __restrict__ sumW, double invDivW,
    const double* __restrict__ sumH, double invDivH,
    const float* __restrict__ bias,
    int8_t* __restrict__ binOut, bf16_t* __restrict__ hOut,
    double* __restrict__ habs)
{
    const int K = 2048;                           // bytes per row
    __shared__ __align__(16) int8_t sA[128 * 128];
    __shared__ __align__(16) int8_t sB[128 * 128];
    const int t = threadIdx.x;
    const int lane = t & 63;
    const int wave = t >> 6;
    const int wr = wave >> 1, wc = wave & 1;
    const int qa = lane >> 4, rA = lane & 15;
    const size_t bm = (size_t)blockIdx.y * 128, bn = (size_t)blockIdx.x * 128;

    i32x4 acc[4][4] = {};

    const int8_t* Abase = A + bm * (size_t)K;
    const int8_t* Bbase = B + bn * (size_t)K;

    const int swz = rA & 7;
    const int offb0 = ((0 + qa) ^ swz) * 16;      // k-half 0: k in [0,64)
    const int offb1 = ((4 + qa) ^ swz) * 16;      // k-half 1: k in [64,128)
    const int arow = wr * 64 + rA;
    const int brow = wc * 64 + rA;

    for (int k0 = 0; k0 < K; k0 += 128) {
        #pragma unroll
        for (int i = 0; i < 4; ++i) {
            int c = i * 256 + t;
            int row = c >> 3, cc = c & 7;
            int ccg = cc ^ (row & 7);
            GLD_LDS16(Abase + (size_t)row * K + k0 + ccg * 16, &sA[c * 16]);
        }
        #pragma unroll
        for (int i = 0; i < 4; ++i) {
            int c = i * 256 + t;
            int row = c >> 3, cc = c & 7;
            int ccg = cc ^ (row & 7);
            GLD_LDS16(Bbase + (size_t)row * K + k0 + ccg * 16, &sB[c * 16]);
        }
        __syncthreads();

        {   // k-half 0
            i32x4 fa[4], fb[4];
            #pragma unroll
            for (int i = 0; i < 4; ++i) {
                fa[i] = *(const i32x4*)&sA[(arow + i * 16) * 128 + offb0];
                fb[i] = *(const i32x4*)&sB[(brow + i * 16) * 128 + offb0];
            }
            #pragma unroll
            for (int i = 0; i < 4; ++i)
                #pragma unroll
                for (int j = 0; j < 4; ++j)
                    acc[i][j] = __builtin_amdgcn_mfma_i32_16x16x64_i8(fa[i], fb[j], acc[i][j], 0, 0, 0);
        }
        {   // k-half 1
            i32x4 fa[4], fb[4];
            #pragma unroll
            for (int i = 0; i < 4; ++i) {
                fa[i] = *(const i32x4*)&sA[(arow + i * 16) * 128 + offb1];
                fb[i] = *(const i32x4*)&sB[(brow + i * 16) * 128 + offb1];
            }
            #pragma unroll
            for (int i = 0; i < 4; ++i)
                #pragma unroll
                for (int j = 0; j < 4; ++j)
                    acc[i][j] = __builtin_amdgcn_mfma_i32_16x16x64_i8(fa[i], fb[j], acc[i][j], 0, 0, 0);
        }
        __syncthreads();
    }

    const double scale = sumW[0] * invDivW * sumH[0] * invDivH;
    double hs = 0.0;
    #pragma unroll
    for (int i = 0; i < 4; ++i) {
        #pragma unroll
        for (int j = 0; j < 4; ++j) {
            #pragma unroll
            for (int rr = 0; rr < 4; ++rr) {
                int m = (int)bm + wr * 64 + i * 16 + qa * 4 + rr;
                int n = (int)bn + wc * 64 + j * 16 + rA;
                size_t idx = (size_t)m * 2048 + n;
                double z = (double)acc[i][j][rr] * scale +
                           (n < 2000 ? (double)bias[n] : -1.0);
                if (binOut) binOut[idx] = (int8_t)(z > 0.0 ? 1 : 0);
                if (hOut)   hOut[idx] = (bf16_t)(float)(z > 0.0 ? z : 0.0);
                if (n < 2000 && z > 0.0) hs += z;
            }
        }
    }
    if (habs) block_reduce_atomic_d(hs, habs);
}

// out[8192][10] = h4[:, :2000] @ W5.T + b5  (h4 bf16, memory-bound)
__global__ __launch_bounds__(256) void fc_final(
    const bf16_t* __restrict__ h4, const float* __restrict__ W5,
    const float* __restrict__ b5, float* __restrict__ out)
{
    const int r = blockIdx.x, t = threadIdx.x;
    float acc[10] = {};
    for (int k = t; k < 2000; k += 256) {
        float a = (float)h4[(size_t)r * 2048 + k];
        #pragma unroll
        for (int c = 0; c < 10; ++c) acc[c] += a * W5[c * 2000 + k];
    }
    __shared__ float red[4][10];
    #pragma unroll
    for (int c = 0; c < 10; ++c) {
        float v = acc[c];
        #pragma unroll
        for (int off = 32; off > 0; off >>= 1) v += __shfl_down(v, off);
        if ((t & 63) == 0) red[t >> 6][c] = v;
    }
    __syncthreads();
    if (t < 10) out[(size_t)r * 10 + t] = red[0][t] + red[1][t] + red[2][t] + red[3][t] + b5[t];
}

extern "C" void kernel_launch(void* const* d_in, const int* in_sizes, int n_in,
                              void* d_out, int out_size, void* d_ws, size_t ws_size,
                              hipStream_t stream)
{
    const float* x  = (const float*)d_in[0];
    const float* W1 = (const float*)d_in[1];
    const float* b1 = (const float*)d_in[2];
    const float* W2 = (const float*)d_in[3];
    const float* b2 = (const float*)d_in[4];
    const float* W3 = (const float*)d_in[5];
    const float* b3 = (const float*)d_in[6];
    const float* W4 = (const float*)d_in[7];
    const float* b4 = (const float*)d_in[8];
    const float* W5 = (const float*)d_in[9];
    const float* b5 = (const float*)d_in[10];
    float* out = (float*)d_out;
    (void)ws_size; (void)in_sizes; (void)n_in; (void)out_size;

    const size_t PH = (size_t)8192 * 2048;

    // Workspace: 260.3 MiB (264 proved safe R3/R4; 516 faulted R2)
    char* w = (char*)d_ws;
    double* scD = (double*)w;                     // [0..3]=sum|W1..4|, [4..6]=sum h1..3
    size_t off = 256;
    bf16_t* XLi = (bf16_t*)(w + off); off += (size_t)8192 * 6144 * 2;  // 96 MiB
    bf16_t* XLr = (bf16_t*)(w + off); off += (size_t)8192 * 3072 * 2;  // 48 MiB
    bf16_t* sW1 = (bf16_t*)(w + off); off += (size_t)2048 * 6144 * 2;  // 24 MiB [s|s]
    float*  Ti  = (float*)(w + off);  off += PH * 4;                   // 64 MiB
    int8_t* p0  = (int8_t*)(w + off); off += PH;                       // 16 MiB
    int8_t* sW2 = (int8_t*)(w + off); off += (size_t)2048 * 2048;      // 4 MiB
    int8_t* sW3 = (int8_t*)(w + off); off += (size_t)2048 * 2048;      // 4 MiB
    int8_t* sW4 = (int8_t*)(w + off); off += (size_t)2048 * 2048;      // 4 MiB
    int8_t* p1  = (int8_t*)XLi;                    // XLi dead after L1 GEMMs
    bf16_t* h4  = (bf16_t*)Ti;                     // Ti dead after L1res epilogue

    hipMemsetAsync(w, 0, 256, stream);
    // one fused prep dispatch: W1 signs (bf16 [s|s]), W2-4 signs (i8), x limbs
    prep_all<<<16384, 256, 0, stream>>>(W1, W2, W3, W4, x,
                                        sW1, sW2, sW3, sW4, XLi, XLr, scD);

    dim3 grid(16, 64), blk(256);
    // L1 integer GEMM (exact): Ti = [d1*512|d0] @ [s|s]^T
    gemm_bin<<<grid, blk, 0, stream>>>(XLi, sW1, 6144, 6144, Ti, nullptr,
                                       nullptr, 0.0, 1.0, nullptr, nullptr, nullptr);
    // L1 residual GEMM + fused combine: z1 = mean|W1| * 2^-14 * (Ti + Sr) + b1
    gemm_bin<<<grid, blk, 0, stream>>>(XLr, sW1, 3072, 6144, nullptr, Ti,
                                       scD + 0, 1.0 / 6144000.0, 1.0 / 16384.0,
                                       b1, p0, scD + 4);

    // Layers 2-4: exact i8 GEMMs, double epilogue
    gemm_i8<<<grid, blk, 0, stream>>>(p0, sW2,
                                      scD + 1, 1.0 / 4000000.0, scD + 4, 1.0 / 16384000.0,
                                      b2, p1, nullptr, scD + 5);
    gemm_i8<<<grid, blk, 0, stream>>>(p1, sW3,
                                      scD + 2, 1.0 / 4000000.0, scD + 5, 1.0 / 16384000.0,
                                      b3, p0, nullptr, scD + 6);
    gemm_i8<<<grid, blk, 0, stream>>>(p0, sW4,
                                      scD + 3, 1.0 / 4000000.0, scD + 6, 1.0 / 16384000.0,
                                      b4, nullptr, h4, nullptr);
    fc_final<<<8192, 256, 0, stream>>>(h4, W5, b5, out);
}